// Round 6
// baseline (802.682 us; speedup 1.0000x reference)
//
#include <hip/hip_runtime.h>
#include <math.h>

#define D 128

typedef __attribute__((ext_vector_type(8))) short short8_t;
typedef __attribute__((ext_vector_type(4))) float f32x4;
typedef __attribute__((ext_vector_type(2))) float f32x2;

__device__ __forceinline__ short f2bf(float f) {
  union { float f; unsigned u; } v; v.f = f;
  unsigned r = v.u + 0x7FFFu + ((v.u >> 16) & 1u);  // round-to-nearest-even
  return (short)(r >> 16);
}
__device__ __forceinline__ float bf2f(unsigned u16) {
  union { unsigned u; float f; } v; v.u = u16 << 16; return v.f;
}

// ---------------------------------------------------------------------------
// zero h
// ---------------------------------------------------------------------------
__global__ void zero_kernel(float* __restrict__ h, long n4) {
  long i = (long)blockIdx.x * blockDim.x + threadIdx.x;
  long stride = (long)gridDim.x * blockDim.x;
  f32x4 z = {0.f, 0.f, 0.f, 0.f};
  for (; i < n4; i += stride) ((f32x4*)h)[i] = z;
}

// ---------------------------------------------------------------------------
// prep: Wc = W0@W0 -> bf16 ; W2,Wl -> bf16 ; zero count[]
// ---------------------------------------------------------------------------
__global__ void prep_kernel(const float* __restrict__ W0, const float* __restrict__ W2,
                            const float* __restrict__ Wl,
                            short* __restrict__ Wcb, short* __restrict__ W2b,
                            short* __restrict__ Wlb, int* __restrict__ count, int N) {
  int b = blockIdx.x, t = threadIdx.x;
  if (b < 64) {
    int idx = b * 256 + t;
    int r = idx >> 7, c = idx & 127;
    float s = 0.f;
    for (int k = 0; k < D; ++k) s += W0[r * D + k] * W0[k * D + c];
    Wcb[idx] = f2bf(s);
  } else if (b < 128) {
    int idx = (b - 64) * 256 + t;
    W2b[idx] = f2bf(W2[idx]);
  } else if (b < 192) {
    int idx = (b - 128) * 256 + t;
    Wlb[idx] = f2bf(Wl[idx]);
  } else {
    int idx = (b - 192) * 256 + t;
    if (idx < N) count[idx] = 0;
  }
}

// ---------------------------------------------------------------------------
// histogram of destination indices (4 edges/thread, vectorized read)
// ---------------------------------------------------------------------------
__global__ void hist_kernel(const int* __restrict__ gi, int* __restrict__ count, int E) {
  int t = blockIdx.x * 256 + threadIdx.x;
  int base = t * 4;
  if (base + 3 < E) {
    int4 v = *(const int4*)(gi + base);
    atomicAdd(&count[v.x], 1);
    atomicAdd(&count[v.y], 1);
    atomicAdd(&count[v.z], 1);
    atomicAdd(&count[v.w], 1);
  } else {
    for (int k = base; k < E; ++k) atomicAdd(&count[gi[k]], 1);
  }
}

// ---------------------------------------------------------------------------
// parallel scan, 3 phases (replaces the single-block, single-CU scan)
// ---------------------------------------------------------------------------
__global__ __launch_bounds__(256) void scan_a_kernel(const int* __restrict__ count,
                                                     int* __restrict__ pref,
                                                     int* __restrict__ bsum, int N) {
  __shared__ int ws[4];
  const int tid = threadIdx.x, lane = tid & 63, wave = tid >> 6;
  int i = blockIdx.x * 256 + tid;
  int c = (i < N) ? count[i] : 0;
  int v = c;
#pragma unroll
  for (int o = 1; o < 64; o <<= 1) {
    int u = __shfl_up(v, o, 64);
    if (lane >= o) v += u;
  }
  if (lane == 63) ws[wave] = v;
  __syncthreads();
  int wp = 0;
  for (int w = 0; w < wave; ++w) wp += ws[w];
  if (i < N) pref[i] = wp + v - c;          // exclusive within block
  if (tid == 255) bsum[blockIdx.x] = wp + v; // block total
}

__global__ __launch_bounds__(256) void scan_b_kernel(int* __restrict__ bsum, int nb) {
  __shared__ int ws[4];
  const int tid = threadIdx.x, lane = tid & 63, wave = tid >> 6;
  int c = (tid < nb) ? bsum[tid] : 0;
  int v = c;
#pragma unroll
  for (int o = 1; o < 64; o <<= 1) {
    int u = __shfl_up(v, o, 64);
    if (lane >= o) v += u;
  }
  if (lane == 63) ws[wave] = v;
  __syncthreads();
  int wp = 0;
  for (int w = 0; w < wave; ++w) wp += ws[w];
  if (tid < nb) bsum[tid] = wp + v - c;      // exclusive across blocks
}

__global__ __launch_bounds__(256) void scan_c_kernel(const int* __restrict__ pref,
                                                     const int* __restrict__ bsum,
                                                     int* __restrict__ woff, int N) {
  int i = blockIdx.x * 256 + threadIdx.x;
  if (i < N) woff[i] = pref[i] + bsum[blockIdx.x];
}

// ---------------------------------------------------------------------------
// scatter: CSR by destination. edata[pos] = {e, j, i, 0} — single 16B store
// ---------------------------------------------------------------------------
__global__ void scatter_kernel(const int* __restrict__ gi, const int* __restrict__ gj,
                               int* __restrict__ woff, int4* __restrict__ edata, int E) {
  int e = blockIdx.x * 256 + threadIdx.x;
  if (e < E) {
    int i = gi[e];
    int pos = atomicAdd(&woff[i], 1);
    int4 ed; ed.x = e; ed.y = gj[e]; ed.z = i; ed.w = 0;
    edata[pos] = ed;
  }
}

// ---------------------------------------------------------------------------
// Wxh = x @ Wl^T + bl -> bf16   (bf16 MFMA, 64 rows/block)
// ---------------------------------------------------------------------------
__global__ __launch_bounds__(256, 2) void node_gemm_kernel(
    const float* __restrict__ x, const short* __restrict__ Wlb,
    const float* __restrict__ bl, short* __restrict__ WxhB, int N) {
  __shared__ short Wl_s[D * D];
  const int tid = threadIdx.x;
  const int lane = tid & 63, wave = tid >> 6;
  const int q = lane & 15, g = lane >> 4;

  for (int it = 0; it < 8; ++it) {
    int eoff = (it * 256 + tid) * 8;
    int row = eoff >> 7, col = eoff & 127;
    int scol = col ^ ((row & 7) << 3);
    *(short8_t*)&Wl_s[row * D + scol] = *(const short8_t*)&Wlb[eoff];
  }

  const int rbase = blockIdx.x * 64 + wave * 16;
  int arow = rbase + q; if (arow > N - 1) arow = N - 1;
  short8_t a[4];
  const float* src = x + (size_t)arow * D;
#pragma unroll
  for (int c = 0; c < 4; ++c) {
    int kb = c * 32 + g * 8;
    f32x4 v0 = *(const f32x4*)(src + kb);
    f32x4 v1 = *(const f32x4*)(src + kb + 4);
    short8_t t;
    t[0]=f2bf(v0.x); t[1]=f2bf(v0.y); t[2]=f2bf(v0.z); t[3]=f2bf(v0.w);
    t[4]=f2bf(v1.x); t[5]=f2bf(v1.y); t[6]=f2bf(v1.z); t[7]=f2bf(v1.w);
    a[c] = t;
  }

  __syncthreads();

  f32x4 acc[8];
#pragma unroll
  for (int n = 0; n < 8; ++n) acc[n] = f32x4{0.f, 0.f, 0.f, 0.f};
#pragma unroll
  for (int n = 0; n < 8; ++n) {
    int row = n * 16 + q;
    int sw = (row & 7) << 3;
#pragma unroll
    for (int c = 0; c < 4; ++c) {
      int col = (c * 32 + g * 8) ^ sw;
      short8_t b = *(const short8_t*)&Wl_s[row * D + col];
      acc[n] = __builtin_amdgcn_mfma_f32_16x16x32_bf16(a[c], b, acc[n], 0, 0, 0);
    }
  }

#pragma unroll
  for (int n = 0; n < 8; ++n) {
    int col = n * 16 + q;
    float bias = bl[col];
#pragma unroll
    for (int r = 0; r < 4; ++r) {
      int orow = rbase + g * 4 + r;
      if (orow < N) WxhB[(size_t)orow * D + col] = f2bf(acc[n][r] + bias);
    }
  }
}

// ---------------------------------------------------------------------------
// fused edge kernel v2 (persistent, CSR order, occupancy-first):
//   m = (silu(rbf[e]@Wc^T + b0)) @ W2^T + b2 ; h[i] += segmented sum m ⊙ Wxh[j]
// Weights read directly from global (64 KB, L1/L2-resident) — NO weight LDS.
// LDS = 16 KB m-transpose tiles only -> 4 blocks/CU (VGPR-capped via
// __launch_bounds__(256,4)). No __syncthreads in the loop; TLP hides latency.
// ---------------------------------------------------------------------------
__global__ __launch_bounds__(256, 4) void fused_edge_kernel(
    const float* __restrict__ rbf, const float* __restrict__ b0v,
    const float* __restrict__ b2v, const short* __restrict__ Wcb,
    const short* __restrict__ W2b, const short* __restrict__ WxhB,
    const int4* __restrict__ edata, float* __restrict__ h, int E, int ntiles) {
  __shared__ short m_s[4][16 * D];

  const int tid = threadIdx.x;
  const int lane = tid & 63, wave = tid >> 6;
  const int q = lane & 15, g = lane >> 4;

  float b0r[8], b2r[8];
#pragma unroll
  for (int n = 0; n < 8; ++n) { b0r[n] = b0v[n * 16 + q]; b2r[n] = b2v[n * 16 + q]; }

  short* ms = &m_s[wave][0];

  for (int tile = blockIdx.x; tile < ntiles; tile += gridDim.x) {
    const int eb = tile * 64 + wave * 16;
    int eq = eb + q; if (eq > E - 1) eq = E - 1;
    const int4 ed = edata[eq];

    // gather Wxh[j] row fragments early — latency hides under both GEMMs
    unsigned wv[16];
#pragma unroll
    for (int r = 0; r < 16; ++r) {
      int jr = __shfl(ed.y, r, 64);
      wv[r] = *(const unsigned*)&WxhB[(size_t)jr * D + lane * 2];
    }

    // load + convert rbf row -> A fragments
    short8_t a[4];
    {
      const float* src = rbf + (size_t)ed.x * D;
#pragma unroll
      for (int c = 0; c < 4; ++c) {
        f32x4 v0 = *(const f32x4*)(src + c * 32 + g * 8);
        f32x4 v1 = *(const f32x4*)(src + c * 32 + g * 8 + 4);
        short8_t t;
        t[0]=f2bf(v0.x); t[1]=f2bf(v0.y); t[2]=f2bf(v0.z); t[3]=f2bf(v0.w);
        t[4]=f2bf(v1.x); t[5]=f2bf(v1.y); t[6]=f2bf(v1.z); t[7]=f2bf(v1.w);
        a[c] = t;
      }
    }

    // GEMM1: u = rbf @ Wc^T   (B-fragments streamed from global/L2)
    f32x4 acc[8];
#pragma unroll
    for (int n = 0; n < 8; ++n) acc[n] = f32x4{0.f, 0.f, 0.f, 0.f};
#pragma unroll
    for (int n = 0; n < 8; ++n) {
      int row = n * 16 + q;
#pragma unroll
      for (int c = 0; c < 4; ++c) {
        short8_t b = *(const short8_t*)&Wcb[row * D + c * 32 + g * 8];
        acc[n] = __builtin_amdgcn_mfma_f32_16x16x32_bf16(a[c], b, acc[n], 0, 0, 0);
      }
    }

    // silu(u + b0) -> wave-private LDS tile (bf16, swizzled) for transpose
#pragma unroll
    for (int n = 0; n < 8; ++n) {
      int col = n * 16 + q;
#pragma unroll
      for (int r = 0; r < 4; ++r) {
        int row = g * 4 + r;
        float u = acc[n][r] + b0r[n];
        float s = u / (1.0f + __expf(-u));
        ms[row * D + (col ^ ((row & 7) << 3))] = f2bf(s);
      }
    }

    // read transposed A fragments (same-wave LDS round trip)
    short8_t a2[4];
    {
      int sw = (q & 7) << 3;
#pragma unroll
      for (int c = 0; c < 4; ++c) {
        int col = (c * 32 + g * 8) ^ sw;
        a2[c] = *(const short8_t*)&ms[q * D + col];
      }
    }

    // GEMM2: m = silu(u) @ W2^T   (B-fragments from global/L2)
    f32x4 acc2[8];
#pragma unroll
    for (int n = 0; n < 8; ++n) acc2[n] = f32x4{0.f, 0.f, 0.f, 0.f};
#pragma unroll
    for (int n = 0; n < 8; ++n) {
      int row = n * 16 + q;
#pragma unroll
      for (int c = 0; c < 4; ++c) {
        short8_t b = *(const short8_t*)&W2b[row * D + c * 32 + g * 8];
        acc2[n] = __builtin_amdgcn_mfma_f32_16x16x32_bf16(a2[c], b, acc2[n], 0, 0, 0);
      }
    }

    // m + b2 -> bf16 back into the wave tile
#pragma unroll
    for (int n = 0; n < 8; ++n) {
      int col = n * 16 + q;
#pragma unroll
      for (int r = 0; r < 4; ++r) {
        int row = g * 4 + r;
        ms[row * D + (col ^ ((row & 7) << 3))] = f2bf(acc2[n][r] + b2r[n]);
      }
    }

    // segmented reduce: lane owns cols {2*lane, 2*lane+1}; rows sorted by i
    int nv = E - eb; if (nv > 16) nv = 16;
    float a0 = 0.f, a1 = 0.f;
    int cur = -1;
#pragma unroll
    for (int r = 0; r < 16; ++r) {
      if (r < nv) {
        int ir = __shfl(ed.z, r, 64);
        if (ir != cur) {
          if (cur >= 0) {
            float* dst = &h[(size_t)cur * D + lane * 2];
            __hip_atomic_fetch_add(dst, a0, __ATOMIC_RELAXED, __HIP_MEMORY_SCOPE_AGENT);
            __hip_atomic_fetch_add(dst + 1, a1, __ATOMIC_RELAXED, __HIP_MEMORY_SCOPE_AGENT);
            a0 = a1 = 0.f;
          }
          cur = ir;
        }
        unsigned mv = *(const unsigned*)&ms[r * D + ((lane * 2) ^ ((r & 7) << 3))];
        a0 += bf2f(mv & 0xffffu) * bf2f(wv[r] & 0xffffu);
        a1 += bf2f(mv >> 16) * bf2f(wv[r] >> 16);
      }
    }
    if (cur >= 0) {
      float* dst = &h[(size_t)cur * D + lane * 2];
      __hip_atomic_fetch_add(dst, a0, __ATOMIC_RELAXED, __HIP_MEMORY_SCOPE_AGENT);
      __hip_atomic_fetch_add(dst + 1, a1, __ATOMIC_RELAXED, __HIP_MEMORY_SCOPE_AGENT);
    }
  }
}

// ---------------------------------------------------------------------------
// LayerNorm over h = x + agg : one wave per row
// ---------------------------------------------------------------------------
__global__ __launch_bounds__(256) void ln_kernel(const float* __restrict__ agg,
                                                 const float* __restrict__ x,
                                                 const float* __restrict__ gamma,
                                                 const float* __restrict__ beta,
                                                 float* __restrict__ out, int N) {
  int wave = threadIdx.x >> 6, lane = threadIdx.x & 63;
  long row = (long)blockIdx.x * 4 + wave;
  if (row >= N) return;
  int c = lane * 2;
  f32x2 av = *(const f32x2*)&agg[row * D + c];
  f32x2 xv = *(const f32x2*)&x[row * D + c];
  float h0 = av.x + xv.x, h1 = av.y + xv.y;
  float sum = h0 + h1;
  float sq = h0 * h0 + h1 * h1;
#pragma unroll
  for (int o = 32; o; o >>= 1) {
    sum += __shfl_xor(sum, o, 64);
    sq += __shfl_xor(sq, o, 64);
  }
  float mu = sum * (1.0f / 128.0f);
  float var = sq * (1.0f / 128.0f) - mu * mu;
  float rstd = rsqrtf(var + 1e-5f);
  f32x2 gv = *(const f32x2*)&gamma[c];
  f32x2 bv = *(const f32x2*)&beta[c];
  f32x2 ov;
  ov.x = (h0 - mu) * rstd * gv.x + bv.x;
  ov.y = (h1 - mu) * rstd * gv.y + bv.y;
  *(f32x2*)&out[row * D + c] = ov;
}

// ---------------------------------------------------------------------------
extern "C" void kernel_launch(void* const* d_in, const int* in_sizes, int n_in,
                              void* d_out, int out_size, void* d_ws, size_t ws_size,
                              hipStream_t stream) {
  const float* x    = (const float*)d_in[0];
  const int*   gi   = (const int*)d_in[1];
  const int*   gj   = (const int*)d_in[2];
  const float* rbf  = (const float*)d_in[3];
  const float* Wl   = (const float*)d_in[4];
  const float* bl   = (const float*)d_in[5];
  const float* W0   = (const float*)d_in[6];
  const float* b0   = (const float*)d_in[7];
  const float* W2   = (const float*)d_in[8];
  const float* b2   = (const float*)d_in[9];
  const float* gam  = (const float*)d_in[10];
  const float* bet  = (const float*)d_in[11];

  const int N = in_sizes[0] / D;  // 50000
  const int E = in_sizes[1];      // 600000

  char* ws = (char*)d_ws;
  size_t off = 0;
  float* h    = (float*)(ws + off); off += (size_t)N * D * 4;   // agg (zeroed)
  short* WxhB = (short*)(ws + off); off += (size_t)N * D * 2;
  int4*  edat = (int4*)(ws + off);  off += (size_t)E * 16;      // 16B-aligned
  int*   cnt  = (int*)(ws + off);   off += (size_t)N * 4;
  int*   pref = (int*)(ws + off);   off += (size_t)N * 4;
  int*   woff = (int*)(ws + off);   off += (size_t)N * 4;
  int*   bsum = (int*)(ws + off);   off += 1024;
  short* Wcb  = (short*)(ws + off); off += D * D * 2;
  short* W2b  = (short*)(ws + off); off += D * D * 2;
  short* Wlb  = (short*)(ws + off); off += D * D * 2;

  const int ntiles = (E + 63) / 64;
  const int nb = (N + 255) / 256;  // 196 <= 256

  zero_kernel<<<2048, 256, 0, stream>>>(h, (long)N * D / 4);
  prep_kernel<<<192 + nb, 256, 0, stream>>>(W0, W2, Wl, Wcb, W2b, Wlb, cnt, N);
  hist_kernel<<<(E / 4 + 255) / 256, 256, 0, stream>>>(gi, cnt, E);
  scan_a_kernel<<<nb, 256, 0, stream>>>(cnt, pref, bsum, N);
  scan_b_kernel<<<1, 256, 0, stream>>>(bsum, nb);
  scan_c_kernel<<<nb, 256, 0, stream>>>(pref, bsum, woff, N);
  scatter_kernel<<<(E + 255) / 256, 256, 0, stream>>>(gi, gj, woff, edat, E);
  node_gemm_kernel<<<(N + 63) / 64, 256, 0, stream>>>(x, Wlb, bl, WxhB, N);
  fused_edge_kernel<<<1024, 256, 0, stream>>>(rbf, b0, b2, Wcb, W2b, WxhB,
                                              edat, h, E, ntiles);
  ln_kernel<<<(N + 3) / 4, 256, 0, stream>>>(h, x, gam, bet, (float*)d_out, N);
}

// Round 7
// 482.049 us; speedup vs baseline: 1.6651x; 1.6651x over previous
//
#include <hip/hip_runtime.h>
#include <math.h>

#define D 128

typedef __attribute__((ext_vector_type(8))) short short8_t;
typedef __attribute__((ext_vector_type(4))) float f32x4;
typedef __attribute__((ext_vector_type(2))) float f32x2;

__device__ __forceinline__ short f2bf(float f) {
  union { float f; unsigned u; } v; v.f = f;
  unsigned r = v.u + 0x7FFFu + ((v.u >> 16) & 1u);  // round-to-nearest-even
  return (short)(r >> 16);
}
__device__ __forceinline__ float bf2f(unsigned u16) {
  union { unsigned u; float f; } v; v.u = u16 << 16; return v.f;
}

// ---------------------------------------------------------------------------
// prep: Wc = W0@W0 -> bf16 ; W2,Wl -> bf16 ; zero count[] ; zero h
// blocks: [0,64) Wc | [64,128) W2 | [128,192) Wl | [192,192+nb) cnt | rest: h
// ---------------------------------------------------------------------------
__global__ void prep_kernel(const float* __restrict__ W0, const float* __restrict__ W2,
                            const float* __restrict__ Wl,
                            short* __restrict__ Wcb, short* __restrict__ W2b,
                            short* __restrict__ Wlb, int* __restrict__ count,
                            float* __restrict__ h, int N, int nb, long h4) {
  int b = blockIdx.x, t = threadIdx.x;
  if (b < 64) {
    int idx = b * 256 + t;
    int r = idx >> 7, c = idx & 127;
    float s = 0.f;
    for (int k = 0; k < D; ++k) s += W0[r * D + k] * W0[k * D + c];
    Wcb[idx] = f2bf(s);
  } else if (b < 128) {
    int idx = (b - 64) * 256 + t;
    W2b[idx] = f2bf(W2[idx]);
  } else if (b < 192) {
    int idx = (b - 128) * 256 + t;
    Wlb[idx] = f2bf(Wl[idx]);
  } else if (b < 192 + nb) {
    int idx = (b - 192) * 256 + t;
    if (idx < N) count[idx] = 0;
  } else {
    long i = (long)(b - 192 - nb) * 256 + t;
    long stride = (long)(gridDim.x - 192 - nb) * 256;
    f32x4 z = {0.f, 0.f, 0.f, 0.f};
    for (; i < h4; i += stride) ((f32x4*)h)[i] = z;
  }
}

// ---------------------------------------------------------------------------
// histogram of destination indices (4 edges/thread, vectorized read)
// ---------------------------------------------------------------------------
__global__ void hist_kernel(const int* __restrict__ gi, int* __restrict__ count, int E) {
  int t = blockIdx.x * 256 + threadIdx.x;
  int base = t * 4;
  if (base + 3 < E) {
    int4 v = *(const int4*)(gi + base);
    atomicAdd(&count[v.x], 1);
    atomicAdd(&count[v.y], 1);
    atomicAdd(&count[v.z], 1);
    atomicAdd(&count[v.w], 1);
  } else {
    for (int k = base; k < E; ++k) atomicAdd(&count[gi[k]], 1);
  }
}

// ---------------------------------------------------------------------------
// scan phase A: per-block exclusive prefix + block sums
// ---------------------------------------------------------------------------
__global__ __launch_bounds__(256) void scan_a_kernel(const int* __restrict__ count,
                                                     int* __restrict__ pref,
                                                     int* __restrict__ bsum, int N) {
  __shared__ int ws[4];
  const int tid = threadIdx.x, lane = tid & 63, wave = tid >> 6;
  int i = blockIdx.x * 256 + tid;
  int c = (i < N) ? count[i] : 0;
  int v = c;
#pragma unroll
  for (int o = 1; o < 64; o <<= 1) {
    int u = __shfl_up(v, o, 64);
    if (lane >= o) v += u;
  }
  if (lane == 63) ws[wave] = v;
  __syncthreads();
  int wp = 0;
  for (int w = 0; w < wave; ++w) wp += ws[w];
  if (i < N) pref[i] = wp + v - c;          // exclusive within block
  if (tid == 255) bsum[blockIdx.x] = wp + v; // block total
}

// ---------------------------------------------------------------------------
// scan phase C: woff[i] = pref[i] + sum(bsum[0..bid))  (bid <= ~196)
// ---------------------------------------------------------------------------
__global__ __launch_bounds__(256) void scan_c_kernel(const int* __restrict__ pref,
                                                     const int* __restrict__ bsum,
                                                     int* __restrict__ woff, int N) {
  __shared__ int base_s;
  const int tid = threadIdx.x, lane = tid & 63;
  if (tid < 64) {
    int p = 0;
    for (int k = lane; k < blockIdx.x; k += 64) p += bsum[k];
#pragma unroll
    for (int o = 32; o; o >>= 1) p += __shfl_xor(p, o, 64);
    if (lane == 0) base_s = p;
  }
  __syncthreads();
  int i = blockIdx.x * 256 + tid;
  if (i < N) woff[i] = pref[i] + base_s;
}

// ---------------------------------------------------------------------------
// scatter: CSR by destination. edata[pos] = {e, j, i, 0} — single 16B store
// ---------------------------------------------------------------------------
__global__ void scatter_kernel(const int* __restrict__ gi, const int* __restrict__ gj,
                               int* __restrict__ woff, int4* __restrict__ edata, int E) {
  int e = blockIdx.x * 256 + threadIdx.x;
  if (e < E) {
    int i = gi[e];
    int pos = atomicAdd(&woff[i], 1);
    int4 ed; ed.x = e; ed.y = gj[e]; ed.z = i; ed.w = 0;
    edata[pos] = ed;
  }
}

// ---------------------------------------------------------------------------
// Wxh = x @ Wl^T + bl -> bf16   (bf16 MFMA, 64 rows/block)
// ---------------------------------------------------------------------------
__global__ __launch_bounds__(256, 2) void node_gemm_kernel(
    const float* __restrict__ x, const short* __restrict__ Wlb,
    const float* __restrict__ bl, short* __restrict__ WxhB, int N) {
  __shared__ short Wl_s[D * D];
  const int tid = threadIdx.x;
  const int lane = tid & 63, wave = tid >> 6;
  const int q = lane & 15, g = lane >> 4;

  for (int it = 0; it < 8; ++it) {
    int eoff = (it * 256 + tid) * 8;
    int row = eoff >> 7, col = eoff & 127;
    int scol = col ^ ((row & 7) << 3);
    *(short8_t*)&Wl_s[row * D + scol] = *(const short8_t*)&Wlb[eoff];
  }

  const int rbase = blockIdx.x * 64 + wave * 16;
  int arow = rbase + q; if (arow > N - 1) arow = N - 1;
  short8_t a[4];
  const float* src = x + (size_t)arow * D;
#pragma unroll
  for (int c = 0; c < 4; ++c) {
    int kb = c * 32 + g * 8;
    f32x4 v0 = *(const f32x4*)(src + kb);
    f32x4 v1 = *(const f32x4*)(src + kb + 4);
    short8_t t;
    t[0]=f2bf(v0.x); t[1]=f2bf(v0.y); t[2]=f2bf(v0.z); t[3]=f2bf(v0.w);
    t[4]=f2bf(v1.x); t[5]=f2bf(v1.y); t[6]=f2bf(v1.z); t[7]=f2bf(v1.w);
    a[c] = t;
  }

  __syncthreads();

  f32x4 acc[8];
#pragma unroll
  for (int n = 0; n < 8; ++n) acc[n] = f32x4{0.f, 0.f, 0.f, 0.f};
#pragma unroll
  for (int n = 0; n < 8; ++n) {
    int row = n * 16 + q;
    int sw = (row & 7) << 3;
#pragma unroll
    for (int c = 0; c < 4; ++c) {
      int col = (c * 32 + g * 8) ^ sw;
      short8_t b = *(const short8_t*)&Wl_s[row * D + col];
      acc[n] = __builtin_amdgcn_mfma_f32_16x16x32_bf16(a[c], b, acc[n], 0, 0, 0);
    }
  }

#pragma unroll
  for (int n = 0; n < 8; ++n) {
    int col = n * 16 + q;
    float bias = bl[col];
#pragma unroll
    for (int r = 0; r < 4; ++r) {
      int orow = rbase + g * 4 + r;
      if (orow < N) WxhB[(size_t)orow * D + col] = f2bf(acc[n][r] + bias);
    }
  }
}

// ---------------------------------------------------------------------------
// fused edge kernel v3 (persistent, CSR order, 1024-thread blocks):
//   m = (silu(rbf[e]@Wc^T + b0)) @ W2^T + b2 ; h[i] += segmented sum m ⊙ Wxh[j]
// Weights in LDS (round-6 showed global weights thrash: FETCH 1.48 GB).
// 16 waves/block, LDS = 64K weights + 16x4K m-tiles = 128 KB -> 1 block/CU
// = 4 waves/SIMD (2x round-5's latency hiding). No syncthreads in the loop.
// ---------------------------------------------------------------------------
__global__ __launch_bounds__(1024, 4) void fused_edge_kernel(
    const float* __restrict__ rbf, const float* __restrict__ b0v,
    const float* __restrict__ b2v, const short* __restrict__ Wcb,
    const short* __restrict__ W2b, const short* __restrict__ WxhB,
    const int4* __restrict__ edata, float* __restrict__ h, int E, int ntiles) {
  __shared__ short Wc_s[D * D];
  __shared__ short W2_s[D * D];
  __shared__ short m_s[16][16 * D];

  const int tid = threadIdx.x;
  const int lane = tid & 63, wave = tid >> 6;   // wave 0..15
  const int q = lane & 15, g = lane >> 4;

  // stage both weight matrices (bf16, XOR-swizzled rows); 2 iters x 1024 thr
  for (int it = 0; it < 2; ++it) {
    int eoff = (it * 1024 + tid) * 8;
    int row = eoff >> 7, col = eoff & 127;
    int scol = col ^ ((row & 7) << 3);
    *(short8_t*)&Wc_s[row * D + scol] = *(const short8_t*)&Wcb[eoff];
    *(short8_t*)&W2_s[row * D + scol] = *(const short8_t*)&W2b[eoff];
  }

  float b0r[8], b2r[8];
#pragma unroll
  for (int n = 0; n < 8; ++n) { b0r[n] = b0v[n * 16 + q]; b2r[n] = b2v[n * 16 + q]; }

  __syncthreads();

  short* ms = &m_s[wave][0];

  for (int tile = blockIdx.x; tile < ntiles; tile += gridDim.x) {
    const int eb = tile * 256 + wave * 16;      // 256 edges/tile, 16/wave
    int eq = eb + q; if (eq > E - 1) eq = E - 1; if (eq < 0) eq = 0;
    const int4 ed = edata[eq];

    // gather Wxh[j] row fragments early — latency hides under both GEMMs
    unsigned wv[16];
#pragma unroll
    for (int r = 0; r < 16; ++r) {
      int jr = __shfl(ed.y, r, 64);
      wv[r] = *(const unsigned*)&WxhB[(size_t)jr * D + lane * 2];
    }

    // load + convert rbf row -> A fragments
    short8_t a[4];
    {
      const float* src = rbf + (size_t)ed.x * D;
#pragma unroll
      for (int c = 0; c < 4; ++c) {
        f32x4 v0 = *(const f32x4*)(src + c * 32 + g * 8);
        f32x4 v1 = *(const f32x4*)(src + c * 32 + g * 8 + 4);
        short8_t t;
        t[0]=f2bf(v0.x); t[1]=f2bf(v0.y); t[2]=f2bf(v0.z); t[3]=f2bf(v0.w);
        t[4]=f2bf(v1.x); t[5]=f2bf(v1.y); t[6]=f2bf(v1.z); t[7]=f2bf(v1.w);
        a[c] = t;
      }
    }

    // GEMM1: u = rbf @ Wc^T
    f32x4 acc[8];
#pragma unroll
    for (int n = 0; n < 8; ++n) acc[n] = f32x4{0.f, 0.f, 0.f, 0.f};
#pragma unroll
    for (int n = 0; n < 8; ++n) {
      int row = n * 16 + q;
      int sw = (row & 7) << 3;
#pragma unroll
      for (int c = 0; c < 4; ++c) {
        int col = (c * 32 + g * 8) ^ sw;
        short8_t b = *(const short8_t*)&Wc_s[row * D + col];
        acc[n] = __builtin_amdgcn_mfma_f32_16x16x32_bf16(a[c], b, acc[n], 0, 0, 0);
      }
    }

    // silu(u + b0) -> wave-private LDS tile (bf16, swizzled) for transpose
#pragma unroll
    for (int n = 0; n < 8; ++n) {
      int col = n * 16 + q;
#pragma unroll
      for (int r = 0; r < 4; ++r) {
        int row = g * 4 + r;
        float u = acc[n][r] + b0r[n];
        float s = u / (1.0f + __expf(-u));
        ms[row * D + (col ^ ((row & 7) << 3))] = f2bf(s);
      }
    }

    // read transposed A fragments (same-wave LDS round trip)
    short8_t a2[4];
    {
      int sw = (q & 7) << 3;
#pragma unroll
      for (int c = 0; c < 4; ++c) {
        int col = (c * 32 + g * 8) ^ sw;
        a2[c] = *(const short8_t*)&ms[q * D + col];
      }
    }

    // GEMM2: m = silu(u) @ W2^T
    f32x4 acc2[8];
#pragma unroll
    for (int n = 0; n < 8; ++n) acc2[n] = f32x4{0.f, 0.f, 0.f, 0.f};
#pragma unroll
    for (int n = 0; n < 8; ++n) {
      int row = n * 16 + q;
      int sw = (row & 7) << 3;
#pragma unroll
      for (int c = 0; c < 4; ++c) {
        int col = (c * 32 + g * 8) ^ sw;
        short8_t b = *(const short8_t*)&W2_s[row * D + col];
        acc2[n] = __builtin_amdgcn_mfma_f32_16x16x32_bf16(a2[c], b, acc2[n], 0, 0, 0);
      }
    }

    // m + b2 -> bf16 back into the wave tile
#pragma unroll
    for (int n = 0; n < 8; ++n) {
      int col = n * 16 + q;
#pragma unroll
      for (int r = 0; r < 4; ++r) {
        int row = g * 4 + r;
        ms[row * D + (col ^ ((row & 7) << 3))] = f2bf(acc2[n][r] + b2r[n]);
      }
    }

    // segmented reduce: lane owns cols {2*lane, 2*lane+1}; rows sorted by i
    int nv = E - eb; if (nv > 16) nv = 16;
    float a0 = 0.f, a1 = 0.f;
    int cur = -1;
#pragma unroll
    for (int r = 0; r < 16; ++r) {
      if (r < nv) {
        int ir = __shfl(ed.z, r, 64);
        if (ir != cur) {
          if (cur >= 0) {
            float* dst = &h[(size_t)cur * D + lane * 2];
            __hip_atomic_fetch_add(dst, a0, __ATOMIC_RELAXED, __HIP_MEMORY_SCOPE_AGENT);
            __hip_atomic_fetch_add(dst + 1, a1, __ATOMIC_RELAXED, __HIP_MEMORY_SCOPE_AGENT);
            a0 = a1 = 0.f;
          }
          cur = ir;
        }
        unsigned mv = *(const unsigned*)&ms[r * D + ((lane * 2) ^ ((r & 7) << 3))];
        a0 += bf2f(mv & 0xffffu) * bf2f(wv[r] & 0xffffu);
        a1 += bf2f(mv >> 16) * bf2f(wv[r] >> 16);
      }
    }
    if (cur >= 0) {
      float* dst = &h[(size_t)cur * D + lane * 2];
      __hip_atomic_fetch_add(dst, a0, __ATOMIC_RELAXED, __HIP_MEMORY_SCOPE_AGENT);
      __hip_atomic_fetch_add(dst + 1, a1, __ATOMIC_RELAXED, __HIP_MEMORY_SCOPE_AGENT);
    }
  }
}

// ---------------------------------------------------------------------------
// LayerNorm over h = x + agg : one wave per row
// ---------------------------------------------------------------------------
__global__ __launch_bounds__(256) void ln_kernel(const float* __restrict__ agg,
                                                 const float* __restrict__ x,
                                                 const float* __restrict__ gamma,
                                                 const float* __restrict__ beta,
                                                 float* __restrict__ out, int N) {
  int wave = threadIdx.x >> 6, lane = threadIdx.x & 63;
  long row = (long)blockIdx.x * 4 + wave;
  if (row >= N) return;
  int c = lane * 2;
  f32x2 av = *(const f32x2*)&agg[row * D + c];
  f32x2 xv = *(const f32x2*)&x[row * D + c];
  float h0 = av.x + xv.x, h1 = av.y + xv.y;
  float sum = h0 + h1;
  float sq = h0 * h0 + h1 * h1;
#pragma unroll
  for (int o = 32; o; o >>= 1) {
    sum += __shfl_xor(sum, o, 64);
    sq += __shfl_xor(sq, o, 64);
  }
  float mu = sum * (1.0f / 128.0f);
  float var = sq * (1.0f / 128.0f) - mu * mu;
  float rstd = rsqrtf(var + 1e-5f);
  f32x2 gv = *(const f32x2*)&gamma[c];
  f32x2 bv = *(const f32x2*)&beta[c];
  f32x2 ov;
  ov.x = (h0 - mu) * rstd * gv.x + bv.x;
  ov.y = (h1 - mu) * rstd * gv.y + bv.y;
  *(f32x2*)&out[row * D + c] = ov;
}

// ---------------------------------------------------------------------------
extern "C" void kernel_launch(void* const* d_in, const int* in_sizes, int n_in,
                              void* d_out, int out_size, void* d_ws, size_t ws_size,
                              hipStream_t stream) {
  const float* x    = (const float*)d_in[0];
  const int*   gi   = (const int*)d_in[1];
  const int*   gj   = (const int*)d_in[2];
  const float* rbf  = (const float*)d_in[3];
  const float* Wl   = (const float*)d_in[4];
  const float* bl   = (const float*)d_in[5];
  const float* W0   = (const float*)d_in[6];
  const float* b0   = (const float*)d_in[7];
  const float* W2   = (const float*)d_in[8];
  const float* b2   = (const float*)d_in[9];
  const float* gam  = (const float*)d_in[10];
  const float* bet  = (const float*)d_in[11];

  const int N = in_sizes[0] / D;  // 50000
  const int E = in_sizes[1];      // 600000

  char* ws = (char*)d_ws;
  size_t off = 0;
  float* h    = (float*)(ws + off); off += (size_t)N * D * 4;   // agg (zeroed)
  short* WxhB = (short*)(ws + off); off += (size_t)N * D * 2;
  int4*  edat = (int4*)(ws + off);  off += (size_t)E * 16;      // 16B-aligned
  int*   cnt  = (int*)(ws + off);   off += (size_t)N * 4;
  int*   pref = (int*)(ws + off);   off += (size_t)N * 4;
  int*   woff = (int*)(ws + off);   off += (size_t)N * 4;
  int*   bsum = (int*)(ws + off);   off += 1024;
  short* Wcb  = (short*)(ws + off); off += D * D * 2;
  short* W2b  = (short*)(ws + off); off += D * D * 2;
  short* Wlb  = (short*)(ws + off); off += D * D * 2;

  const int ntiles = (E + 255) / 256;   // 256 edges per tile
  const int nb = (N + 255) / 256;       // 196

  prep_kernel<<<192 + nb + 1024, 256, 0, stream>>>(W0, W2, Wl, Wcb, W2b, Wlb,
                                                   cnt, h, N, nb, (long)N * D / 4);
  hist_kernel<<<(E / 4 + 255) / 256, 256, 0, stream>>>(gi, cnt, E);
  scan_a_kernel<<<nb, 256, 0, stream>>>(cnt, pref, bsum, N);
  scan_c_kernel<<<nb, 256, 0, stream>>>(pref, bsum, woff, N);
  scatter_kernel<<<(E + 255) / 256, 256, 0, stream>>>(gi, gj, woff, edat, E);
  node_gemm_kernel<<<(N + 63) / 64, 256, 0, stream>>>(x, Wlb, bl, WxhB, N);
  fused_edge_kernel<<<256, 1024, 0, stream>>>(rbf, b0, b2, Wcb, W2b, WxhB,
                                              edat, h, E, ntiles);
  ln_kernel<<<(N + 3) / 4, 256, 0, stream>>>(h, x, gam, bet, (float*)d_out, N);
}

// Round 8
// 396.692 us; speedup vs baseline: 2.0234x; 1.2152x over previous
//
#include <hip/hip_runtime.h>
#include <math.h>

#define D 128

typedef __attribute__((ext_vector_type(8))) short short8_t;
typedef __attribute__((ext_vector_type(4))) float f32x4;
typedef __attribute__((ext_vector_type(2))) float f32x2;

__device__ __forceinline__ short f2bf(float f) {
  union { float f; unsigned u; } v; v.f = f;
  unsigned r = v.u + 0x7FFFu + ((v.u >> 16) & 1u);  // round-to-nearest-even
  return (short)(r >> 16);
}
__device__ __forceinline__ float bf2f(unsigned u16) {
  union { unsigned u; float f; } v; v.u = u16 << 16; return v.f;
}

// ---------------------------------------------------------------------------
// prep: Wc = W0@W0 -> bf16 ; W2,Wl -> bf16 ; zero count[] ; zero h
// ---------------------------------------------------------------------------
__global__ void prep_kernel(const float* __restrict__ W0, const float* __restrict__ W2,
                            const float* __restrict__ Wl,
                            short* __restrict__ Wcb, short* __restrict__ W2b,
                            short* __restrict__ Wlb, int* __restrict__ count,
                            float* __restrict__ h, int N, int nb, long h4) {
  int b = blockIdx.x, t = threadIdx.x;
  if (b < 64) {
    int idx = b * 256 + t;
    int r = idx >> 7, c = idx & 127;
    float s = 0.f;
    for (int k = 0; k < D; ++k) s += W0[r * D + k] * W0[k * D + c];
    Wcb[idx] = f2bf(s);
  } else if (b < 128) {
    int idx = (b - 64) * 256 + t;
    W2b[idx] = f2bf(W2[idx]);
  } else if (b < 192) {
    int idx = (b - 128) * 256 + t;
    Wlb[idx] = f2bf(Wl[idx]);
  } else if (b < 192 + nb) {
    int idx = (b - 192) * 256 + t;
    if (idx < N) count[idx] = 0;
  } else {
    long i = (long)(b - 192 - nb) * 256 + t;
    long stride = (long)(gridDim.x - 192 - nb) * 256;
    f32x4 z = {0.f, 0.f, 0.f, 0.f};
    for (; i < h4; i += stride) ((f32x4*)h)[i] = z;
  }
}

// ---------------------------------------------------------------------------
__global__ void hist_kernel(const int* __restrict__ gi, int* __restrict__ count, int E) {
  int t = blockIdx.x * 256 + threadIdx.x;
  int base = t * 4;
  if (base + 3 < E) {
    int4 v = *(const int4*)(gi + base);
    atomicAdd(&count[v.x], 1);
    atomicAdd(&count[v.y], 1);
    atomicAdd(&count[v.z], 1);
    atomicAdd(&count[v.w], 1);
  } else {
    for (int k = base; k < E; ++k) atomicAdd(&count[gi[k]], 1);
  }
}

// ---------------------------------------------------------------------------
__global__ __launch_bounds__(256) void scan_a_kernel(const int* __restrict__ count,
                                                     int* __restrict__ pref,
                                                     int* __restrict__ bsum, int N) {
  __shared__ int ws[4];
  const int tid = threadIdx.x, lane = tid & 63, wave = tid >> 6;
  int i = blockIdx.x * 256 + tid;
  int c = (i < N) ? count[i] : 0;
  int v = c;
#pragma unroll
  for (int o = 1; o < 64; o <<= 1) {
    int u = __shfl_up(v, o, 64);
    if (lane >= o) v += u;
  }
  if (lane == 63) ws[wave] = v;
  __syncthreads();
  int wp = 0;
  for (int w = 0; w < wave; ++w) wp += ws[w];
  if (i < N) pref[i] = wp + v - c;
  if (tid == 255) bsum[blockIdx.x] = wp + v;
}

__global__ __launch_bounds__(256) void scan_c_kernel(const int* __restrict__ pref,
                                                     const int* __restrict__ bsum,
                                                     int* __restrict__ woff, int N) {
  __shared__ int base_s;
  const int tid = threadIdx.x, lane = tid & 63;
  if (tid < 64) {
    int p = 0;
    for (int k = lane; k < blockIdx.x; k += 64) p += bsum[k];
#pragma unroll
    for (int o = 32; o; o >>= 1) p += __shfl_xor(p, o, 64);
    if (lane == 0) base_s = p;
  }
  __syncthreads();
  int i = blockIdx.x * 256 + tid;
  if (i < N) woff[i] = pref[i] + base_s;
}

// ---------------------------------------------------------------------------
__global__ void scatter_kernel(const int* __restrict__ gi, const int* __restrict__ gj,
                               int* __restrict__ woff, int4* __restrict__ edata, int E) {
  int e = blockIdx.x * 256 + threadIdx.x;
  if (e < E) {
    int i = gi[e];
    int pos = atomicAdd(&woff[i], 1);
    int4 ed; ed.x = e; ed.y = gj[e]; ed.z = i; ed.w = 0;
    edata[pos] = ed;
  }
}

// ---------------------------------------------------------------------------
// Wxh = x @ Wl^T + bl -> bf16
// ---------------------------------------------------------------------------
__global__ __launch_bounds__(256, 2) void node_gemm_kernel(
    const float* __restrict__ x, const short* __restrict__ Wlb,
    const float* __restrict__ bl, short* __restrict__ WxhB, int N) {
  __shared__ short Wl_s[D * D];
  const int tid = threadIdx.x;
  const int lane = tid & 63, wave = tid >> 6;
  const int q = lane & 15, g = lane >> 4;

  for (int it = 0; it < 8; ++it) {
    int eoff = (it * 256 + tid) * 8;
    int row = eoff >> 7, col = eoff & 127;
    int scol = col ^ ((row & 7) << 3);
    *(short8_t*)&Wl_s[row * D + scol] = *(const short8_t*)&Wlb[eoff];
  }

  const int rbase = blockIdx.x * 64 + wave * 16;
  int arow = rbase + q; if (arow > N - 1) arow = N - 1;
  short8_t a[4];
  const float* src = x + (size_t)arow * D;
#pragma unroll
  for (int c = 0; c < 4; ++c) {
    int kb = c * 32 + g * 8;
    f32x4 v0 = *(const f32x4*)(src + kb);
    f32x4 v1 = *(const f32x4*)(src + kb + 4);
    short8_t t;
    t[0]=f2bf(v0.x); t[1]=f2bf(v0.y); t[2]=f2bf(v0.z); t[3]=f2bf(v0.w);
    t[4]=f2bf(v1.x); t[5]=f2bf(v1.y); t[6]=f2bf(v1.z); t[7]=f2bf(v1.w);
    a[c] = t;
  }

  __syncthreads();

  f32x4 acc[8];
#pragma unroll
  for (int n = 0; n < 8; ++n) acc[n] = f32x4{0.f, 0.f, 0.f, 0.f};
#pragma unroll
  for (int n = 0; n < 8; ++n) {
    int row = n * 16 + q;
    int sw = (row & 7) << 3;
#pragma unroll
    for (int c = 0; c < 4; ++c) {
      int col = (c * 32 + g * 8) ^ sw;
      short8_t b = *(const short8_t*)&Wl_s[row * D + col];
      acc[n] = __builtin_amdgcn_mfma_f32_16x16x32_bf16(a[c], b, acc[n], 0, 0, 0);
    }
  }

#pragma unroll
  for (int n = 0; n < 8; ++n) {
    int col = n * 16 + q;
    float bias = bl[col];
#pragma unroll
    for (int r = 0; r < 4; ++r) {
      int orow = rbase + g * 4 + r;
      if (orow < N) WxhB[(size_t)orow * D + col] = f2bf(acc[n][r] + bias);
    }
  }
}

// ---------------------------------------------------------------------------
// fused edge kernel v4: 1024 threads, weights in LDS, 1-deep pipeline.
// amdgpu_waves_per_eu(4,4): LDS (128 KB) pins 1 block/CU = 4 waves/SIMD, so
// tell the allocator to use the full 128-VGPR budget (r7's 64-VGPR alloc
// spilled the ~110-reg working set every iteration).
// ---------------------------------------------------------------------------
__global__ __launch_bounds__(1024)
__attribute__((amdgpu_waves_per_eu(4, 4)))
void fused_edge_kernel(
    const float* __restrict__ rbf, const float* __restrict__ b0v,
    const float* __restrict__ b2v, const short* __restrict__ Wcb,
    const short* __restrict__ W2b, const short* __restrict__ WxhB,
    const int4* __restrict__ edata, float* __restrict__ h, int E, int ntiles) {
  __shared__ short Wc_s[D * D];
  __shared__ short W2_s[D * D];
  __shared__ short m_s[16][16 * D];

  const int tid = threadIdx.x;
  const int lane = tid & 63, wave = tid >> 6;   // wave 0..15
  const int q = lane & 15, g = lane >> 4;

  for (int it = 0; it < 2; ++it) {
    int eoff = (it * 1024 + tid) * 8;
    int row = eoff >> 7, col = eoff & 127;
    int scol = col ^ ((row & 7) << 3);
    *(short8_t*)&Wc_s[row * D + scol] = *(const short8_t*)&Wcb[eoff];
    *(short8_t*)&W2_s[row * D + scol] = *(const short8_t*)&W2b[eoff];
  }

  float b0r[8], b2r[8];
#pragma unroll
  for (int n = 0; n < 8; ++n) { b0r[n] = b0v[n * 16 + q]; b2r[n] = b2v[n * 16 + q]; }

  __syncthreads();

  short* ms = &m_s[wave][0];

  int tile = blockIdx.x;
  if (tile >= ntiles) return;

  // prologue: first tile's edata + rbf (converted to bf16 at load)
  int eb = tile * 256 + wave * 16;
  int eq = eb + q; if (eq > E - 1) eq = E - 1;
  int4 ed = edata[eq];
  short8_t a[4];
  {
    const float* src = rbf + (size_t)ed.x * D;
#pragma unroll
    for (int c = 0; c < 4; ++c) {
      f32x4 v0 = *(const f32x4*)(src + c * 32 + g * 8);
      f32x4 v1 = *(const f32x4*)(src + c * 32 + g * 8 + 4);
      short8_t t;
      t[0]=f2bf(v0.x); t[1]=f2bf(v0.y); t[2]=f2bf(v0.z); t[3]=f2bf(v0.w);
      t[4]=f2bf(v1.x); t[5]=f2bf(v1.y); t[6]=f2bf(v1.z); t[7]=f2bf(v1.w);
      a[c] = t;
    }
  }

  while (true) {
    const int ntile = tile + gridDim.x;
    const bool hnext = ntile < ntiles;
    const int ptile = hnext ? ntile : tile;

    // next tile's edata — issue first, needed in ~2 GEMMs
    const int neb = ptile * 256 + wave * 16;
    int neq = neb + q; if (neq > E - 1) neq = E - 1;
    int4 ed2 = edata[neq];

    // current tile's Wxh[j] gather — needed at the reduce (end of tile)
    unsigned wv[16];
#pragma unroll
    for (int r = 0; r < 16; ++r) {
      int jr = __shfl(ed.y, r, 64);
      wv[r] = *(const unsigned*)&WxhB[(size_t)jr * D + lane * 2];
    }

    // GEMM1: u = rbf @ Wc^T
    f32x4 acc[8];
#pragma unroll
    for (int n = 0; n < 8; ++n) acc[n] = f32x4{0.f, 0.f, 0.f, 0.f};
#pragma unroll
    for (int n = 0; n < 8; ++n) {
      int row = n * 16 + q;
      int sw = (row & 7) << 3;
#pragma unroll
      for (int c = 0; c < 4; ++c) {
        int col = (c * 32 + g * 8) ^ sw;
        short8_t b = *(const short8_t*)&Wc_s[row * D + col];
        acc[n] = __builtin_amdgcn_mfma_f32_16x16x32_bf16(a[c], b, acc[n], 0, 0, 0);
      }
    }

    // next tile's rbf load+convert — hides under GEMM2 + reduce
    short8_t a_next[4];
    {
      const float* src2 = rbf + (size_t)ed2.x * D;
#pragma unroll
      for (int c = 0; c < 4; ++c) {
        f32x4 v0 = *(const f32x4*)(src2 + c * 32 + g * 8);
        f32x4 v1 = *(const f32x4*)(src2 + c * 32 + g * 8 + 4);
        short8_t t;
        t[0]=f2bf(v0.x); t[1]=f2bf(v0.y); t[2]=f2bf(v0.z); t[3]=f2bf(v0.w);
        t[4]=f2bf(v1.x); t[5]=f2bf(v1.y); t[6]=f2bf(v1.z); t[7]=f2bf(v1.w);
        a_next[c] = t;
      }
    }

    // silu(u + b0) -> wave-private LDS tile (bf16, swizzled)
#pragma unroll
    for (int n = 0; n < 8; ++n) {
      int col = n * 16 + q;
#pragma unroll
      for (int r = 0; r < 4; ++r) {
        int row = g * 4 + r;
        float u = acc[n][r] + b0r[n];
        float s = u / (1.0f + __expf(-u));
        ms[row * D + (col ^ ((row & 7) << 3))] = f2bf(s);
      }
    }

    // read transposed A fragments
    short8_t a2[4];
    {
      int sw = (q & 7) << 3;
#pragma unroll
      for (int c = 0; c < 4; ++c) {
        int col = (c * 32 + g * 8) ^ sw;
        a2[c] = *(const short8_t*)&ms[q * D + col];
      }
    }

    // GEMM2: m = silu(u) @ W2^T  (reuse acc)
#pragma unroll
    for (int n = 0; n < 8; ++n) acc[n] = f32x4{0.f, 0.f, 0.f, 0.f};
#pragma unroll
    for (int n = 0; n < 8; ++n) {
      int row = n * 16 + q;
      int sw = (row & 7) << 3;
#pragma unroll
      for (int c = 0; c < 4; ++c) {
        int col = (c * 32 + g * 8) ^ sw;
        short8_t b = *(const short8_t*)&W2_s[row * D + col];
        acc[n] = __builtin_amdgcn_mfma_f32_16x16x32_bf16(a2[c], b, acc[n], 0, 0, 0);
      }
    }

    // m + b2 -> bf16 back into the wave tile
#pragma unroll
    for (int n = 0; n < 8; ++n) {
      int col = n * 16 + q;
#pragma unroll
      for (int r = 0; r < 4; ++r) {
        int row = g * 4 + r;
        ms[row * D + (col ^ ((row & 7) << 3))] = f2bf(acc[n][r] + b2r[n]);
      }
    }

    // segmented reduce: lane owns cols {2*lane, 2*lane+1}; rows sorted by i
    int nv = E - eb; if (nv > 16) nv = 16;
    float a0 = 0.f, a1 = 0.f;
    int cur = -1;
#pragma unroll
    for (int r = 0; r < 16; ++r) {
      if (r < nv) {
        int ir = __shfl(ed.z, r, 64);
        if (ir != cur) {
          if (cur >= 0) {
            float* dst = &h[(size_t)cur * D + lane * 2];
            __hip_atomic_fetch_add(dst, a0, __ATOMIC_RELAXED, __HIP_MEMORY_SCOPE_AGENT);
            __hip_atomic_fetch_add(dst + 1, a1, __ATOMIC_RELAXED, __HIP_MEMORY_SCOPE_AGENT);
            a0 = a1 = 0.f;
          }
          cur = ir;
        }
        unsigned mv = *(const unsigned*)&ms[r * D + ((lane * 2) ^ ((r & 7) << 3))];
        a0 += bf2f(mv & 0xffffu) * bf2f(wv[r] & 0xffffu);
        a1 += bf2f(mv >> 16) * bf2f(wv[r] >> 16);
      }
    }
    if (cur >= 0) {
      float* dst = &h[(size_t)cur * D + lane * 2];
      __hip_atomic_fetch_add(dst, a0, __ATOMIC_RELAXED, __HIP_MEMORY_SCOPE_AGENT);
      __hip_atomic_fetch_add(dst + 1, a1, __ATOMIC_RELAXED, __HIP_MEMORY_SCOPE_AGENT);
    }

    if (!hnext) break;
    tile = ntile; eb = neb; ed = ed2;
#pragma unroll
    for (int c = 0; c < 4; ++c) a[c] = a_next[c];
  }
}

// ---------------------------------------------------------------------------
// LayerNorm over h = x + agg
// ---------------------------------------------------------------------------
__global__ __launch_bounds__(256) void ln_kernel(const float* __restrict__ agg,
                                                 const float* __restrict__ x,
                                                 const float* __restrict__ gamma,
                                                 const float* __restrict__ beta,
                                                 float* __restrict__ out, int N) {
  int wave = threadIdx.x >> 6, lane = threadIdx.x & 63;
  long row = (long)blockIdx.x * 4 + wave;
  if (row >= N) return;
  int c = lane * 2;
  f32x2 av = *(const f32x2*)&agg[row * D + c];
  f32x2 xv = *(const f32x2*)&x[row * D + c];
  float h0 = av.x + xv.x, h1 = av.y + xv.y;
  float sum = h0 + h1;
  float sq = h0 * h0 + h1 * h1;
#pragma unroll
  for (int o = 32; o; o >>= 1) {
    sum += __shfl_xor(sum, o, 64);
    sq += __shfl_xor(sq, o, 64);
  }
  float mu = sum * (1.0f / 128.0f);
  float var = sq * (1.0f / 128.0f) - mu * mu;
  float rstd = rsqrtf(var + 1e-5f);
  f32x2 gv = *(const f32x2*)&gamma[c];
  f32x2 bv = *(const f32x2*)&beta[c];
  f32x2 ov;
  ov.x = (h0 - mu) * rstd * gv.x + bv.x;
  ov.y = (h1 - mu) * rstd * gv.y + bv.y;
  *(f32x2*)&out[row * D + c] = ov;
}

// ---------------------------------------------------------------------------
extern "C" void kernel_launch(void* const* d_in, const int* in_sizes, int n_in,
                              void* d_out, int out_size, void* d_ws, size_t ws_size,
                              hipStream_t stream) {
  const float* x    = (const float*)d_in[0];
  const int*   gi   = (const int*)d_in[1];
  const int*   gj   = (const int*)d_in[2];
  const float* rbf  = (const float*)d_in[3];
  const float* Wl   = (const float*)d_in[4];
  const float* bl   = (const float*)d_in[5];
  const float* W0   = (const float*)d_in[6];
  const float* b0   = (const float*)d_in[7];
  const float* W2   = (const float*)d_in[8];
  const float* b2   = (const float*)d_in[9];
  const float* gam  = (const float*)d_in[10];
  const float* bet  = (const float*)d_in[11];

  const int N = in_sizes[0] / D;  // 50000
  const int E = in_sizes[1];      // 600000

  char* ws = (char*)d_ws;
  size_t off = 0;
  float* h    = (float*)(ws + off); off += (size_t)N * D * 4;
  short* WxhB = (short*)(ws + off); off += (size_t)N * D * 2;
  int4*  edat = (int4*)(ws + off);  off += (size_t)E * 16;
  int*   cnt  = (int*)(ws + off);   off += (size_t)N * 4;
  int*   pref = (int*)(ws + off);   off += (size_t)N * 4;
  int*   woff = (int*)(ws + off);   off += (size_t)N * 4;
  int*   bsum = (int*)(ws + off);   off += 1024;
  short* Wcb  = (short*)(ws + off); off += D * D * 2;
  short* W2b  = (short*)(ws + off); off += D * D * 2;
  short* Wlb  = (short*)(ws + off); off += D * D * 2;

  const int ntiles = (E + 255) / 256;
  const int nb = (N + 255) / 256;

  prep_kernel<<<192 + nb + 1024, 256, 0, stream>>>(W0, W2, Wl, Wcb, W2b, Wlb,
                                                   cnt, h, N, nb, (long)N * D / 4);
  hist_kernel<<<(E / 4 + 255) / 256, 256, 0, stream>>>(gi, cnt, E);
  scan_a_kernel<<<nb, 256, 0, stream>>>(cnt, pref, bsum, N);
  scan_c_kernel<<<nb, 256, 0, stream>>>(pref, bsum, woff, N);
  scatter_kernel<<<(E + 255) / 256, 256, 0, stream>>>(gi, gj, woff, edat, E);
  node_gemm_kernel<<<(N + 63) / 64, 256, 0, stream>>>(x, Wlb, bl, WxhB, N);
  fused_edge_kernel<<<256, 1024, 0, stream>>>(rbf, b0, b2, Wcb, W2b, WxhB,
                                              edat, h, E, ntiles);
  ln_kernel<<<(N + 3) / 4, 256, 0, stream>>>(h, x, gam, bet, (float*)d_out, N);
}

// Round 9
// 254.456 us; speedup vs baseline: 3.1545x; 1.5590x over previous
//
#include <hip/hip_runtime.h>
#include <math.h>

#define D 128

typedef __attribute__((ext_vector_type(8))) short short8_t;
typedef __attribute__((ext_vector_type(4))) float f32x4;
typedef __attribute__((ext_vector_type(2))) float f32x2;

__device__ __forceinline__ short f2bf(float f) {
  union { float f; unsigned u; } v; v.f = f;
  unsigned r = v.u + 0x7FFFu + ((v.u >> 16) & 1u);  // round-to-nearest-even
  return (short)(r >> 16);
}
__device__ __forceinline__ float bf2f(unsigned u16) {
  union { unsigned u; float f; } v; v.u = u16 << 16; return v.f;
}

// ---------------------------------------------------------------------------
// prep: Wc = W0@W0 -> bf16 ; W2,Wl -> bf16 ; zero count[] ; zero h
// ---------------------------------------------------------------------------
__global__ void prep_kernel(const float* __restrict__ W0, const float* __restrict__ W2,
                            const float* __restrict__ Wl,
                            short* __restrict__ Wcb, short* __restrict__ W2b,
                            short* __restrict__ Wlb, int* __restrict__ count,
                            float* __restrict__ h, int N, int nb, long h4) {
  int b = blockIdx.x, t = threadIdx.x;
  if (b < 64) {
    int idx = b * 256 + t;
    int r = idx >> 7, c = idx & 127;
    float s = 0.f;
    for (int k = 0; k < D; ++k) s += W0[r * D + k] * W0[k * D + c];
    Wcb[idx] = f2bf(s);
  } else if (b < 128) {
    int idx = (b - 64) * 256 + t;
    W2b[idx] = f2bf(W2[idx]);
  } else if (b < 192) {
    int idx = (b - 128) * 256 + t;
    Wlb[idx] = f2bf(Wl[idx]);
  } else if (b < 192 + nb) {
    int idx = (b - 192) * 256 + t;
    if (idx < N) count[idx] = 0;
  } else {
    long i = (long)(b - 192 - nb) * 256 + t;
    long stride = (long)(gridDim.x - 192 - nb) * 256;
    f32x4 z = {0.f, 0.f, 0.f, 0.f};
    for (; i < h4; i += stride) ((f32x4*)h)[i] = z;
  }
}

// ---------------------------------------------------------------------------
__global__ void hist_kernel(const int* __restrict__ gi, int* __restrict__ count, int E) {
  int t = blockIdx.x * 256 + threadIdx.x;
  int base = t * 4;
  if (base + 3 < E) {
    int4 v = *(const int4*)(gi + base);
    atomicAdd(&count[v.x], 1);
    atomicAdd(&count[v.y], 1);
    atomicAdd(&count[v.z], 1);
    atomicAdd(&count[v.w], 1);
  } else {
    for (int k = base; k < E; ++k) atomicAdd(&count[gi[k]], 1);
  }
}

// ---------------------------------------------------------------------------
__global__ __launch_bounds__(256) void scan_a_kernel(const int* __restrict__ count,
                                                     int* __restrict__ pref,
                                                     int* __restrict__ bsum, int N) {
  __shared__ int ws[4];
  const int tid = threadIdx.x, lane = tid & 63, wave = tid >> 6;
  int i = blockIdx.x * 256 + tid;
  int c = (i < N) ? count[i] : 0;
  int v = c;
#pragma unroll
  for (int o = 1; o < 64; o <<= 1) {
    int u = __shfl_up(v, o, 64);
    if (lane >= o) v += u;
  }
  if (lane == 63) ws[wave] = v;
  __syncthreads();
  int wp = 0;
  for (int w = 0; w < wave; ++w) wp += ws[w];
  if (i < N) pref[i] = wp + v - c;
  if (tid == 255) bsum[blockIdx.x] = wp + v;
}

__global__ __launch_bounds__(256) void scan_c_kernel(const int* __restrict__ pref,
                                                     const int* __restrict__ bsum,
                                                     int* __restrict__ woff, int N) {
  __shared__ int base_s;
  const int tid = threadIdx.x, lane = tid & 63;
  if (tid < 64) {
    int p = 0;
    for (int k = lane; k < blockIdx.x; k += 64) p += bsum[k];
#pragma unroll
    for (int o = 32; o; o >>= 1) p += __shfl_xor(p, o, 64);
    if (lane == 0) base_s = p;
  }
  __syncthreads();
  int i = blockIdx.x * 256 + tid;
  if (i < N) woff[i] = pref[i] + base_s;
}

// ---------------------------------------------------------------------------
__global__ void scatter_kernel(const int* __restrict__ gi, const int* __restrict__ gj,
                               int* __restrict__ woff, int4* __restrict__ edata, int E) {
  int e = blockIdx.x * 256 + threadIdx.x;
  if (e < E) {
    int i = gi[e];
    int pos = atomicAdd(&woff[i], 1);
    int4 ed; ed.x = e; ed.y = gj[e]; ed.z = i; ed.w = 0;
    edata[pos] = ed;
  }
}

// ---------------------------------------------------------------------------
// Wxh = x @ Wl^T + bl -> bf16
// ---------------------------------------------------------------------------
__global__ __launch_bounds__(256, 2) void node_gemm_kernel(
    const float* __restrict__ x, const short* __restrict__ Wlb,
    const float* __restrict__ bl, short* __restrict__ WxhB, int N) {
  __shared__ short Wl_s[D * D];
  const int tid = threadIdx.x;
  const int lane = tid & 63, wave = tid >> 6;
  const int q = lane & 15, g = lane >> 4;

  for (int it = 0; it < 8; ++it) {
    int eoff = (it * 256 + tid) * 8;
    int row = eoff >> 7, col = eoff & 127;
    int scol = col ^ ((row & 7) << 3);
    *(short8_t*)&Wl_s[row * D + scol] = *(const short8_t*)&Wlb[eoff];
  }

  const int rbase = blockIdx.x * 64 + wave * 16;
  int arow = rbase + q; if (arow > N - 1) arow = N - 1;
  short8_t a[4];
  const float* src = x + (size_t)arow * D;
#pragma unroll
  for (int c = 0; c < 4; ++c) {
    int kb = c * 32 + g * 8;
    f32x4 v0 = *(const f32x4*)(src + kb);
    f32x4 v1 = *(const f32x4*)(src + kb + 4);
    short8_t t;
    t[0]=f2bf(v0.x); t[1]=f2bf(v0.y); t[2]=f2bf(v0.z); t[3]=f2bf(v0.w);
    t[4]=f2bf(v1.x); t[5]=f2bf(v1.y); t[6]=f2bf(v1.z); t[7]=f2bf(v1.w);
    a[c] = t;
  }

  __syncthreads();

  f32x4 acc[8];
#pragma unroll
  for (int n = 0; n < 8; ++n) acc[n] = f32x4{0.f, 0.f, 0.f, 0.f};
#pragma unroll
  for (int n = 0; n < 8; ++n) {
    int row = n * 16 + q;
    int sw = (row & 7) << 3;
#pragma unroll
    for (int c = 0; c < 4; ++c) {
      int col = (c * 32 + g * 8) ^ sw;
      short8_t b = *(const short8_t*)&Wl_s[row * D + col];
      acc[n] = __builtin_amdgcn_mfma_f32_16x16x32_bf16(a[c], b, acc[n], 0, 0, 0);
    }
  }

#pragma unroll
  for (int n = 0; n < 8; ++n) {
    int col = n * 16 + q;
    float bias = bl[col];
#pragma unroll
    for (int r = 0; r < 4; ++r) {
      int orow = rbase + g * 4 + r;
      if (orow < N) WxhB[(size_t)orow * D + col] = f2bf(acc[n][r] + bias);
    }
  }
}

// ---------------------------------------------------------------------------
// fused edge kernel v5: 256 threads, 2 blocks/CU, weights in LDS,
// deep prefetch: edata 3 tiles ahead, rbf/Wxh 1 tile ahead — ALL issued at
// tile start so every load has >= 1 full tile (~500+ cy) of compute cover.
// (r8's 1024-thread variant allocated only 64 VGPR and spilled; 256-thread
//  launch_bounds(256,2) kernels get a real register budget.)
// ---------------------------------------------------------------------------
__global__ __launch_bounds__(256, 2) void fused_edge_kernel(
    const float* __restrict__ rbf, const float* __restrict__ b0v,
    const float* __restrict__ b2v, const short* __restrict__ Wcb,
    const short* __restrict__ W2b, const short* __restrict__ WxhB,
    const int4* __restrict__ edata, float* __restrict__ h, int E, int ntiles) {
  __shared__ short Wc_s[D * D];
  __shared__ short W2_s[D * D];
  __shared__ short m_s[4][16 * D];

  const int tid = threadIdx.x;
  const int lane = tid & 63, wave = tid >> 6;
  const int q = lane & 15, g = lane >> 4;

  for (int it = 0; it < 8; ++it) {
    int eoff = (it * 256 + tid) * 8;
    int row = eoff >> 7, col = eoff & 127;
    int scol = col ^ ((row & 7) << 3);
    *(short8_t*)&Wc_s[row * D + scol] = *(const short8_t*)&Wcb[eoff];
    *(short8_t*)&W2_s[row * D + scol] = *(const short8_t*)&W2b[eoff];
  }

  float b0r[8], b2r[8];
#pragma unroll
  for (int n = 0; n < 8; ++n) { b0r[n] = b0v[n * 16 + q]; b2r[n] = b2v[n * 16 + q]; }

  __syncthreads();

  short* ms = &m_s[wave][0];
  const int stride = gridDim.x;

  int tile = blockIdx.x;
  if (tile >= ntiles) return;

  // clamped per-lane edata index for an arbitrary tile index
#define EQOF(t) ({ int tc_ = (t) < ntiles ? (t) : ntiles - 1;                  \
                   int e_ = tc_ * 64 + wave * 16 + q;                          \
                   e_ < E ? e_ : E - 1; })

  // prologue: edata 3-deep, rbf + Wxh 1-deep (for tile t)
  int4 ed0 = edata[EQOF(tile)];
  int4 ed1 = edata[EQOF(tile + stride)];
  int4 ed2 = edata[EQOF(tile + 2 * stride)];
  f32x4 rb[8];
  {
    const float* src = rbf + (size_t)ed0.x * D;
#pragma unroll
    for (int c = 0; c < 4; ++c) {
      rb[c * 2]     = *(const f32x4*)(src + c * 32 + g * 8);
      rb[c * 2 + 1] = *(const f32x4*)(src + c * 32 + g * 8 + 4);
    }
  }
  unsigned wv0[16];
#pragma unroll
  for (int r = 0; r < 16; ++r) {
    int jr = __shfl(ed0.y, r, 64);
    wv0[r] = *(const unsigned*)&WxhB[(size_t)jr * D + lane * 2];
  }

  while (true) {
    const bool hnext = (tile + stride) < ntiles;

    // ---- consume rb(t): convert to A fragments (frees rb registers)
    short8_t a[4];
#pragma unroll
    for (int c = 0; c < 4; ++c) {
      f32x4 v0 = rb[c * 2], v1 = rb[c * 2 + 1];
      short8_t t;
      t[0]=f2bf(v0.x); t[1]=f2bf(v0.y); t[2]=f2bf(v0.z); t[3]=f2bf(v0.w);
      t[4]=f2bf(v1.x); t[5]=f2bf(v1.y); t[6]=f2bf(v1.z); t[7]=f2bf(v1.w);
      a[c] = t;
    }

    // ---- issue ALL next-tile loads now (addresses from already-arrived eds)
    int4 ed3 = edata[EQOF(tile + 3 * stride)];
    {
      const float* src = rbf + (size_t)ed1.x * D;   // rbf for t+1
#pragma unroll
      for (int c = 0; c < 4; ++c) {
        rb[c * 2]     = *(const f32x4*)(src + c * 32 + g * 8);
        rb[c * 2 + 1] = *(const f32x4*)(src + c * 32 + g * 8 + 4);
      }
    }
    unsigned wv1[16];                               // Wxh for t+1
#pragma unroll
    for (int r = 0; r < 16; ++r) {
      int jr = __shfl(ed1.y, r, 64);
      wv1[r] = *(const unsigned*)&WxhB[(size_t)jr * D + lane * 2];
    }

    // ---- GEMM1: u = rbf @ Wc^T
    f32x4 acc[8];
#pragma unroll
    for (int n = 0; n < 8; ++n) acc[n] = f32x4{0.f, 0.f, 0.f, 0.f};
#pragma unroll
    for (int n = 0; n < 8; ++n) {
      int row = n * 16 + q;
      int sw = (row & 7) << 3;
#pragma unroll
      for (int c = 0; c < 4; ++c) {
        int col = (c * 32 + g * 8) ^ sw;
        short8_t b = *(const short8_t*)&Wc_s[row * D + col];
        acc[n] = __builtin_amdgcn_mfma_f32_16x16x32_bf16(a[c], b, acc[n], 0, 0, 0);
      }
    }

    // ---- silu(u + b0) -> wave-private LDS tile (bf16, swizzled)
#pragma unroll
    for (int n = 0; n < 8; ++n) {
      int col = n * 16 + q;
#pragma unroll
      for (int r = 0; r < 4; ++r) {
        int row = g * 4 + r;
        float u = acc[n][r] + b0r[n];
        float s = u / (1.0f + __expf(-u));
        ms[row * D + (col ^ ((row & 7) << 3))] = f2bf(s);
      }
    }

    // ---- transposed A fragments
    short8_t a2[4];
    {
      int sw = (q & 7) << 3;
#pragma unroll
      for (int c = 0; c < 4; ++c) {
        int col = (c * 32 + g * 8) ^ sw;
        a2[c] = *(const short8_t*)&ms[q * D + col];
      }
    }

    // ---- GEMM2: m = silu(u) @ W2^T  (reuse acc)
#pragma unroll
    for (int n = 0; n < 8; ++n) acc[n] = f32x4{0.f, 0.f, 0.f, 0.f};
#pragma unroll
    for (int n = 0; n < 8; ++n) {
      int row = n * 16 + q;
      int sw = (row & 7) << 3;
#pragma unroll
      for (int c = 0; c < 4; ++c) {
        int col = (c * 32 + g * 8) ^ sw;
        short8_t b = *(const short8_t*)&W2_s[row * D + col];
        acc[n] = __builtin_amdgcn_mfma_f32_16x16x32_bf16(a2[c], b, acc[n], 0, 0, 0);
      }
    }

    // ---- m + b2 -> bf16 back into the wave tile
#pragma unroll
    for (int n = 0; n < 8; ++n) {
      int col = n * 16 + q;
#pragma unroll
      for (int r = 0; r < 4; ++r) {
        int row = g * 4 + r;
        ms[row * D + (col ^ ((row & 7) << 3))] = f2bf(acc[n][r] + b2r[n]);
      }
    }

    // ---- segmented reduce with wv0/ed0 (rows sorted by destination i)
    const int eb = tile * 64 + wave * 16;
    int nv = E - eb; if (nv > 16) nv = 16;
    float a0 = 0.f, a1 = 0.f;
    int cur = -1;
#pragma unroll
    for (int r = 0; r < 16; ++r) {
      if (r < nv) {
        int ir = __shfl(ed0.z, r, 64);
        if (ir != cur) {
          if (cur >= 0) {
            float* dst = &h[(size_t)cur * D + lane * 2];
            __hip_atomic_fetch_add(dst, a0, __ATOMIC_RELAXED, __HIP_MEMORY_SCOPE_AGENT);
            __hip_atomic_fetch_add(dst + 1, a1, __ATOMIC_RELAXED, __HIP_MEMORY_SCOPE_AGENT);
            a0 = a1 = 0.f;
          }
          cur = ir;
        }
        unsigned mv = *(const unsigned*)&ms[r * D + ((lane * 2) ^ ((r & 7) << 3))];
        a0 += bf2f(mv & 0xffffu) * bf2f(wv0[r] & 0xffffu);
        a1 += bf2f(mv >> 16) * bf2f(wv0[r] >> 16);
      }
    }
    if (cur >= 0) {
      float* dst = &h[(size_t)cur * D + lane * 2];
      __hip_atomic_fetch_add(dst, a0, __ATOMIC_RELAXED, __HIP_MEMORY_SCOPE_AGENT);
      __hip_atomic_fetch_add(dst + 1, a1, __ATOMIC_RELAXED, __HIP_MEMORY_SCOPE_AGENT);
    }

    if (!hnext) break;
    tile += stride;
    ed0 = ed1; ed1 = ed2; ed2 = ed3;
#pragma unroll
    for (int r = 0; r < 16; ++r) wv0[r] = wv1[r];
  }
#undef EQOF
}

// ---------------------------------------------------------------------------
// LayerNorm over h = x + agg
// ---------------------------------------------------------------------------
__global__ __launch_bounds__(256) void ln_kernel(const float* __restrict__ agg,
                                                 const float* __restrict__ x,
                                                 const float* __restrict__ gamma,
                                                 const float* __restrict__ beta,
                                                 float* __restrict__ out, int N) {
  int wave = threadIdx.x >> 6, lane = threadIdx.x & 63;
  long row = (long)blockIdx.x * 4 + wave;
  if (row >= N) return;
  int c = lane * 2;
  f32x2 av = *(const f32x2*)&agg[row * D + c];
  f32x2 xv = *(const f32x2*)&x[row * D + c];
  float h0 = av.x + xv.x, h1 = av.y + xv.y;
  float sum = h0 + h1;
  float sq = h0 * h0 + h1 * h1;
#pragma unroll
  for (int o = 32; o; o >>= 1) {
    sum += __shfl_xor(sum, o, 64);
    sq += __shfl_xor(sq, o, 64);
  }
  float mu = sum * (1.0f / 128.0f);
  float var = sq * (1.0f / 128.0f) - mu * mu;
  float rstd = rsqrtf(var + 1e-5f);
  f32x2 gv = *(const f32x2*)&gamma[c];
  f32x2 bv = *(const f32x2*)&beta[c];
  f32x2 ov;
  ov.x = (h0 - mu) * rstd * gv.x + bv.x;
  ov.y = (h1 - mu) * rstd * gv.y + bv.y;
  *(f32x2*)&out[row * D + c] = ov;
}

// ---------------------------------------------------------------------------
extern "C" void kernel_launch(void* const* d_in, const int* in_sizes, int n_in,
                              void* d_out, int out_size, void* d_ws, size_t ws_size,
                              hipStream_t stream) {
  const float* x    = (const float*)d_in[0];
  const int*   gi   = (const int*)d_in[1];
  const int*   gj   = (const int*)d_in[2];
  const float* rbf  = (const float*)d_in[3];
  const float* Wl   = (const float*)d_in[4];
  const float* bl   = (const float*)d_in[5];
  const float* W0   = (const float*)d_in[6];
  const float* b0   = (const float*)d_in[7];
  const float* W2   = (const float*)d_in[8];
  const float* b2   = (const float*)d_in[9];
  const float* gam  = (const float*)d_in[10];
  const float* bet  = (const float*)d_in[11];

  const int N = in_sizes[0] / D;  // 50000
  const int E = in_sizes[1];      // 600000

  char* ws = (char*)d_ws;
  size_t off = 0;
  float* h    = (float*)(ws + off); off += (size_t)N * D * 4;
  short* WxhB = (short*)(ws + off); off += (size_t)N * D * 2;
  int4*  edat = (int4*)(ws + off);  off += (size_t)E * 16;
  int*   cnt  = (int*)(ws + off);   off += (size_t)N * 4;
  int*   pref = (int*)(ws + off);   off += (size_t)N * 4;
  int*   woff = (int*)(ws + off);   off += (size_t)N * 4;
  int*   bsum = (int*)(ws + off);   off += 1024;
  short* Wcb  = (short*)(ws + off); off += D * D * 2;
  short* W2b  = (short*)(ws + off); off += D * D * 2;
  short* Wlb  = (short*)(ws + off); off += D * D * 2;

  const int ntiles = (E + 63) / 64;     // 64 edges per tile (4 waves x 16)
  const int nb = (N + 255) / 256;

  prep_kernel<<<192 + nb + 1024, 256, 0, stream>>>(W0, W2, Wl, Wcb, W2b, Wlb,
                                                   cnt, h, N, nb, (long)N * D / 4);
  hist_kernel<<<(E / 4 + 255) / 256, 256, 0, stream>>>(gi, cnt, E);
  scan_a_kernel<<<nb, 256, 0, stream>>>(cnt, pref, bsum, N);
  scan_c_kernel<<<nb, 256, 0, stream>>>(pref, bsum, woff, N);
  scatter_kernel<<<(E + 255) / 256, 256, 0, stream>>>(gi, gj, woff, edat, E);
  node_gemm_kernel<<<(N + 63) / 64, 256, 0, stream>>>(x, Wlb, bl, WxhB, N);
  fused_edge_kernel<<<512, 256, 0, stream>>>(rbf, b0, b2, Wcb, W2b, WxhB,
                                             edat, h, E, ntiles);
  ln_kernel<<<(N + 3) / 4, 256, 0, stream>>>(h, x, gam, bet, (float*)d_out, N);
}